// Round 13
// baseline (80.736 us; speedup 1.0000x reference)
//
#include <hip/hip_runtime.h>
#include <math.h>

// 10-qubit real-amplitude circuit simulator, batch 16384, depth 8.
// Layout: 32 lanes per batch element (index bits [4:0] = lane&31),
//         16 x v2f (=32 scalars) per lane; scalar s = u*2 + comp.
// Qubit map: q0..q3 -> u bits 3..0 ; q4 -> float2 component ;
//            q5..q9 -> lane bits 4..0.
// 2 elements per wave (lane bit 5), 8 per 256-thread block.
//
// vs round 12 (DS-latency exposed at ~4 waves/SIMD: dur 77 > max(VALU 56us,
// DS 41us)): __launch_bounds__(256,8) — VGPR demand is 36 (unrolled, proven),
// cap 64 is ample; 8 waves/SIMD doubles latency hiding at the two per-layer
// lgkmcnt wait points. Everything else identical to round 12.

typedef float v2f __attribute__((ext_vector_type(2)));

// ---- cross-lane helpers -------------------------------------------------
template<int CTRL>
__device__ __forceinline__ float dpp_mov(float x) {
  int i = __builtin_bit_cast(int, x);
  i = __builtin_amdgcn_update_dpp(i, i, CTRL, 0xf, 0xf, true);
  return __builtin_bit_cast(float, i);
}
__device__ __forceinline__ float xl1(float x) { return dpp_mov<0xB1>(x); }   // lane^1
__device__ __forceinline__ float xl2(float x) { return dpp_mov<0x4E>(x); }   // lane^2
__device__ __forceinline__ float xl8(float x) { return dpp_mov<0x128>(x); }  // row_ror:8 == lane^8
__device__ __forceinline__ float xl4d(float x) {                             // lane^4 via 2 DPP (VALU)
  return dpp_mov<0x141>(dpp_mov<0x1B>(x));   // row_half_mirror o quad_perm[3,2,1,0]
}
template<int PAT>
__device__ __forceinline__ float swz(float x) {  // ds_swizzle BitMode
  int i = __builtin_amdgcn_ds_swizzle(__builtin_bit_cast(int, x), PAT);
  return __builtin_bit_cast(float, i);
}
__device__ __forceinline__ float xl4(float x)  { return swz<0x101F>(x); }    // lane^4 (epilogue only)
__device__ __forceinline__ float xl16(float x) { return swz<0x401F>(x); }    // lane^16
__device__ __forceinline__ float bperm(int addr, float x) {
  int i = __builtin_amdgcn_ds_bpermute(addr, __builtin_bit_cast(int, x));
  return __builtin_bit_cast(float, i);
}
__device__ __forceinline__ float red32(float x) {
  x += xl1(x); x += xl2(x); x += xl4(x); x += xl8(x); x += xl16(x); return x;
}

// ---- one level of the sum/diff tree -------------------------------------
template<int L2>
__device__ __forceinline__ float tree_level(float* t) {
  float a = 0.f, b = 0.f;
  #pragma unroll
  for (int j = 0; j < L2; ++j) {
    float e = t[2 * j], o = t[2 * j + 1];
    if (j & 1) b += e - o; else a += e - o;
    t[j] = e + o;
  }
  return a + b;
}

__global__ __launch_bounds__(256, 8) void circuit_kernel(
    const float* __restrict__ x, const float* __restrict__ params,
    float* __restrict__ out) {
  __shared__ float csh[160];  // cos/sin of pi*tanh(param)/2, [l*20 + 2q {+1}]

  const int tid  = threadIdx.x;
  const int wv   = tid >> 6;
  const int lane = tid & 63;
  const int h    = lane >> 5;   // element within wave (0..1)
  const int l5   = lane & 31;   // lane within group = index bits [4:0]
  const long elem = (long)blockIdx.x * 8 + wv * 2 + h;

  if (tid < 80) {
    float th = 1.57079632679489662f * tanhf(params[tid]);  // (pi*tanh)/2
    csh[2 * tid]     = cosf(th);
    csh[2 * tid + 1] = sinf(th);
  }

  // bpermute pull map (inverse of push (4,5),(6,7),(8,9),(5,6),(7,8)):
  //   m = l5; b1^=b2; b3^=b4; b0^=b1; b2^=b3; [odd scalar: b4^=1]
  int m = l5 ^ ((l5 & 4) >> 1);   // undo (7,8)
  m ^= (m & 16) >> 1;             // undo (5,6)
  m ^= (m & 2) >> 1;              // undo (8,9)
  m ^= (m & 8) >> 1;              // undo (6,7)
  const int addrE = ((lane & 32) | m) << 2;  // even scalar (.x) source
  const int addrO = addrE ^ 64;              // odd scalar (.y): lane b4 flips

  // ---- load: scalar s at x[s*32 + l5]; s = 2u (+1 for .y) ----------------
  v2f w[16];
  const float* xb = x + elem * 784 + l5;
  #pragma unroll
  for (int u = 0; u < 12; ++u) {
    w[u].x = xb[u * 64];
    w[u].y = xb[u * 64 + 32];
  }
  w[12].x = (l5 < 16) ? xb[768] : 0.f;
  w[12].y = 0.f;
  #pragma unroll
  for (int u = 13; u < 16; ++u) w[u] = (v2f){0.f, 0.f};

  // ---- norm^2 only (normalization deferred to the store) -----------------
  v2f acc = {0.f, 0.f};
  #pragma unroll
  for (int u = 0; u < 13; ++u) acc += w[u] * w[u];
  float nn  = red32(acc.x + acc.y);
  float inv = 1.0f / nn;

  __syncthreads();   // csh ready

  // ---- 8 layers, fully unrolled ------------------------------------------
  #pragma unroll
  for (int l = 0; l < 8; ++l) {
    const float* cl = &csh[l * 20];

    // 1. reg swaps for CNOT (0,1),(2,3)  [renames]
    #pragma unroll
    for (int u = 0; u < 16; ++u) if ((u & 12) == 8) { v2f t = w[u]; w[u] = w[u + 4]; w[u + 4] = t; } // (0,1)
    #pragma unroll
    for (int u = 0; u < 16; ++u) if ((u & 3) == 2) { v2f t = w[u]; w[u] = w[u + 1]; w[u + 1] = t; }  // (2,3)

    // 2. fused cross-lane CNOTs (4,5),(6,7),(8,9),(5,6),(7,8)
    #pragma unroll
    for (int u = 0; u < 16; ++u) {
      w[u].x = bperm(addrE, w[u].x);
      w[u].y = bperm(addrO, w[u].y);
    }

    // 3. reg swaps for CNOT (1,2); (3,4) = component swap for odd u
    #pragma unroll
    for (int u = 0; u < 16; ++u) if ((u & 6) == 4) { v2f t = w[u]; w[u] = w[u + 2]; w[u + 2] = t; }  // (1,2)
    #pragma unroll
    for (int u = 1; u < 16; u += 2) w[u] = __builtin_shufflevector(w[u], w[u], 1, 0);                // (3,4)

    // 4. RY q0..q3 (packed pair rotations over u-bits 3..0)
    { v2f cc = {cl[0], cl[0]}, ss = {cl[1], cl[1]};
      #pragma unroll
      for (int u = 0; u < 16; ++u) if ((u & 8) == 0) {
        v2f a = w[u], b = w[u + 8];
        w[u] = cc * a - ss * b;  w[u + 8] = ss * a + cc * b;
      } }
    { v2f cc = {cl[2], cl[2]}, ss = {cl[3], cl[3]};
      #pragma unroll
      for (int u = 0; u < 16; ++u) if ((u & 4) == 0) {
        v2f a = w[u], b = w[u + 4];
        w[u] = cc * a - ss * b;  w[u + 4] = ss * a + cc * b;
      } }
    { v2f cc = {cl[4], cl[4]}, ss = {cl[5], cl[5]};
      #pragma unroll
      for (int u = 0; u < 16; ++u) if ((u & 2) == 0) {
        v2f a = w[u], b = w[u + 2];
        w[u] = cc * a - ss * b;  w[u + 2] = ss * a + cc * b;
      } }
    { v2f cc = {cl[6], cl[6]}, ss = {cl[7], cl[7]};
      #pragma unroll
      for (int u = 0; u < 16; ++u) if ((u & 1) == 0) {
        v2f a = w[u], b = w[u + 1];
        w[u] = cc * a - ss * b;  w[u + 1] = ss * a + cc * b;
      } }

    // RY q4 (component pair): w' = (c,s)*w.xx + (-s,c)*w.yy
    { v2f A = {cl[8], cl[9]}, B = {-cl[9], cl[8]};
      #pragma unroll
      for (int u = 0; u < 16; ++u) {
        v2f xx = __builtin_shufflevector(w[u], w[u], 0, 0);
        v2f yy = __builtin_shufflevector(w[u], w[u], 1, 1);
        w[u] = A * xx + B * yy;
      } }

    // RY q5 (lane b4, ds_swizzle xor16)  [DS batch 2 of 2]
    { float sn = (lane & 16) ? cl[11] : -cl[11];
      v2f cc = {cl[10], cl[10]}, ssn = {sn, sn};
      #pragma unroll
      for (int u = 0; u < 16; ++u) {
        v2f p = { xl16(w[u].x), xl16(w[u].y) };
        w[u] = cc * w[u] + ssn * p;
      } }
    // RY q6 (lane b3, DPP row_ror:8)
    { float sn = (lane & 8) ? cl[13] : -cl[13];
      v2f cc = {cl[12], cl[12]}, ssn = {sn, sn};
      #pragma unroll
      for (int u = 0; u < 16; ++u) {
        v2f p = { xl8(w[u].x), xl8(w[u].y) };
        w[u] = cc * w[u] + ssn * p;
      } }
    // RY q7 (lane b2) via double-DPP xor4 (VALU pipe)
    { float sn = (lane & 4) ? cl[15] : -cl[15];
      v2f cc = {cl[14], cl[14]}, ssn = {sn, sn};
      #pragma unroll
      for (int u = 0; u < 16; ++u) {
        v2f p = { xl4d(w[u].x), xl4d(w[u].y) };
        w[u] = cc * w[u] + ssn * p;
      } }
    // RY q8 (lane b1, DPP xor2)
    { float sn = (lane & 2) ? cl[17] : -cl[17];
      v2f cc = {cl[16], cl[16]}, ssn = {sn, sn};
      #pragma unroll
      for (int u = 0; u < 16; ++u) {
        v2f p = { xl2(w[u].x), xl2(w[u].y) };
        w[u] = cc * w[u] + ssn * p;
      } }
    // RY q9 (lane b0, DPP xor1)
    { float sn = (lane & 1) ? cl[19] : -cl[19];
      v2f cc = {cl[18], cl[18]}, ssn = {sn, sn};
      #pragma unroll
      for (int u = 0; u < 16; ++u) {
        v2f p = { xl1(w[u].x), xl1(w[u].y) };
        w[u] = cc * w[u] + ssn * p;
      } }
  }

  // ---- expectation values (unnormalized; scaled by inv at the store) -----
  #pragma unroll
  for (int u = 0; u < 16; ++u) w[u] *= w[u];   // probabilities * nn

  float t16[16];
  float a0 = 0.f, a1 = 0.f;
  #pragma unroll
  for (int u = 0; u < 16; ++u) {
    float d = w[u].x - w[u].y;
    if (u & 1) a1 += d; else a0 += d;
    t16[u] = w[u].x + w[u].y;
  }
  float z[10];
  z[4] = red32(a0 + a1);
  z[3] = red32(tree_level<8>(t16));
  z[2] = red32(tree_level<4>(t16));
  z[1] = red32(tree_level<2>(t16));
  z[0] = red32(tree_level<1>(t16));
  float W = t16[0];  // per-lane total (unnormalized) probability
  // lane-bit qubits: signed reductions over the 32-lane group
  { float u = W + xl1(W); u += xl2(u); u += xl4(u); u += xl8(u);  float t = u - xl16(u); z[5] = (lane & 16) ? -t : t; }
  { float u = W + xl1(W); u += xl2(u); u += xl4(u); u += xl16(u); float t = u - xl8(u);  z[6] = (lane & 8)  ? -t : t; }
  { float u = W + xl1(W); u += xl2(u); u += xl8(u); u += xl16(u); float t = u - xl4(u);  z[7] = (lane & 4)  ? -t : t; }
  { float u = W + xl1(W); u += xl4(u); u += xl8(u); u += xl16(u); float t = u - xl2(u);  z[8] = (lane & 2)  ? -t : t; }
  { float u = W + xl2(W); u += xl4(u); u += xl8(u); u += xl16(u); float t = u - xl1(u);  z[9] = (lane & 1)  ? -t : t; }

  // ---- store: lane l5 (<10) writes column l5, normalized -----------------
  float o = z[0];
  #pragma unroll
  for (int j = 1; j < 10; ++j) o = (l5 == j) ? z[j] : o;
  if (l5 < 10) out[elem * 10 + l5] = o * inv;
}

extern "C" void kernel_launch(void* const* d_in, const int* in_sizes, int n_in,
                              void* d_out, int out_size, void* d_ws, size_t ws_size,
                              hipStream_t stream) {
  const float* x      = (const float*)d_in[0];   // [16384, 784]
  const float* params = (const float*)d_in[1];   // [8, 10]
  float* out          = (float*)d_out;           // [16384, 10]
  (void)d_ws; (void)ws_size; (void)in_sizes; (void)n_in; (void)out_size;
  // 16384 elements / 8 per block (2 per wave x 4 waves)
  circuit_kernel<<<2048, 256, 0, stream>>>(x, params, out);
}

// Round 16
// 61.612 us; speedup vs baseline: 1.3104x; 1.3104x over previous
//
#include <hip/hip_runtime.h>
#include <math.h>

// 10-qubit real-amplitude circuit simulator, batch 16384, depth 8.
// Layout: 32 lanes per batch element (index bits [4:0] = lane&31),
//         32 scalar float VGPRs per lane (index bits [9:5] = register index).
// Qubit q <-> index bit (9-q): q0..q4 -> reg bits 4..0 ; q5..q9 -> lane 4..0.
// 2 elements per wave (lane bit 5), 8 per 256-thread block.
//
// vs round 15 (NaN: GLOBAL cos-product 1/C^2 ~ 1e48 overflowed fp32 --
// theta/2 spans (-pi/2,pi/2) so median c ~ 0.5, C ~ 0.5^80):
// tan-form gates kept, but rescale by the layer's product of 10 cos
// factors AT THE END OF EACH LAYER (32 muls/layer). State equals the
// reference amplitudes at every layer boundary; intra-layer growth
// bounded by one layer's 1/prod(c) (~1e3..1e5) -> squares < 1e10. Safe.

// ---- cross-lane helpers -------------------------------------------------
template<int CTRL>
__device__ __forceinline__ float dpp_mov(float x) {
  int i = __builtin_bit_cast(int, x);
  i = __builtin_amdgcn_update_dpp(i, i, CTRL, 0xf, 0xf, true);
  return __builtin_bit_cast(float, i);
}
__device__ __forceinline__ float xl1(float x) { return dpp_mov<0xB1>(x); }   // lane^1
__device__ __forceinline__ float xl2(float x) { return dpp_mov<0x4E>(x); }   // lane^2
__device__ __forceinline__ float xl8(float x) { return dpp_mov<0x128>(x); }  // row_ror:8 == lane^8
__device__ __forceinline__ float xl4d(float x) {                             // lane^4 via 2 DPP (VALU)
  return dpp_mov<0x141>(dpp_mov<0x1B>(x));   // row_half_mirror o quad_perm[3,2,1,0]
}
template<int PAT>
__device__ __forceinline__ float swz(float x) {  // ds_swizzle BitMode
  int i = __builtin_amdgcn_ds_swizzle(__builtin_bit_cast(int, x), PAT);
  return __builtin_bit_cast(float, i);
}
__device__ __forceinline__ float xl4(float x)  { return swz<0x101F>(x); }    // lane^4 (epilogue only)
__device__ __forceinline__ float xl16(float x) { return swz<0x401F>(x); }    // lane^16
__device__ __forceinline__ float bperm(int addr, float x) {
  int i = __builtin_amdgcn_ds_bpermute(addr, __builtin_bit_cast(int, x));
  return __builtin_bit_cast(float, i);
}
__device__ __forceinline__ float red32(float x) {
  x += xl1(x); x += xl2(x); x += xl4(x); x += xl8(x); x += xl16(x); return x;
}

// ---- tan-form RY on a register-bit qubit: (a,b) -> (a - t*b, b + t*a) ---
template<int M>
__device__ __forceinline__ void ry_reg_t(float* v, float t) {
  #pragma unroll
  for (int r = 0; r < 32; ++r) {
    if ((r & M) == 0) {
      float a = v[r], b = v[r + M];
      v[r]     = fmaf(-t, b, a);
      v[r + M] = fmaf( t, a, b);
    }
  }
}

// ---- one level of the sum/diff tree -------------------------------------
template<int L2>
__device__ __forceinline__ float tree_level(float* v) {
  float a = 0.f, b = 0.f;
  #pragma unroll
  for (int j = 0; j < L2; ++j) {
    float e = v[2 * j], o = v[2 * j + 1];
    if (j & 1) b += e - o; else a += e - o;
    v[j] = e + o;
  }
  return a + b;
}

__global__ __launch_bounds__(256, 6) void circuit_kernel(
    const float* __restrict__ x, const float* __restrict__ params,
    float* __restrict__ out) {
  // csh[2g]=tan(th/2), csh[2g+1]=cos(th/2) for gate g=l*10+q;
  // csh[160+l] = prod of layer l's 10 cos factors.
  __shared__ float csh[168];

  const int tid  = threadIdx.x;
  const int wv   = tid >> 6;
  const int lane = tid & 63;
  const int h    = lane >> 5;   // element within wave (0..1)
  const int l5   = lane & 31;   // lane within group = index bits [4:0]
  const long elem = (long)blockIdx.x * 8 + wv * 2 + h;

  if (tid < 80) {
    float th = 1.57079632679489662f * tanhf(params[tid]);  // (pi*tanh)/2
    float c = cosf(th), s = sinf(th);
    csh[2 * tid]     = s / c;   // tan(th/2)
    csh[2 * tid + 1] = c;
  }

  // bpermute pull map (inverse of push (4,5),(6,7),(8,9),(5,6),(7,8)):
  //   m = l5; b1^=b2; b3^=b4; b0^=b1; b2^=b3; [odd r: b4^=1]
  int m = l5 ^ ((l5 & 4) >> 1);   // undo (7,8)
  m ^= (m & 16) >> 1;             // undo (5,6)
  m ^= (m & 2) >> 1;              // undo (8,9)
  m ^= (m & 8) >> 1;              // undo (6,7)
  const int addrE = ((lane & 32) | m) << 2;  // even-r source (byte addr)
  const int addrO = addrE ^ 64;              // odd r: lane b4 additionally flips

  // ---- load: 784 = 24*32 + 16, stride-32 per lane ------------------------
  float v[32];
  const float* xb = x + elem * 784 + l5;
  #pragma unroll
  for (int k = 0; k < 24; ++k) v[k] = xb[k * 32];
  v[24] = (l5 < 16) ? xb[768] : 0.f;
  #pragma unroll
  for (int k = 25; k < 32; ++k) v[k] = 0.f;

  // ---- norm^2 only (normalization deferred to the store) -----------------
  float nn = 0.f;
  #pragma unroll
  for (int k = 0; k < 25; ++k) nn = fmaf(v[k], v[k], nn);
  nn = red32(nn);
  float inv = 1.0f / nn;

  __syncthreads();   // csh t/c entries ready
  if (tid < 8) {     // per-layer scale: product of this layer's 10 cos
    float P = 1.f;
    #pragma unroll
    for (int q = 0; q < 10; ++q) P *= csh[tid * 20 + 2 * q + 1];
    csh[160 + tid] = P;
  }
  __syncthreads();   // layer scales ready

  // ---- 8 layers, fully unrolled, tan-form + per-layer rescale ------------
  #pragma unroll
  for (int l = 0; l < 8; ++l) {
    const float* cl = &csh[l * 20];

    // 1. reg-reg swaps for CNOT (0,1),(2,3)  [free SSA renames]
    #pragma unroll
    for (int r = 0; r < 32; ++r) if ((r & 24) == 16) { float t = v[r]; v[r] = v[r + 8]; v[r + 8] = t; } // (0,1)
    #pragma unroll
    for (int r = 0; r < 32; ++r) if ((r & 6) == 4) { float t = v[r]; v[r] = v[r + 2]; v[r + 2] = t; }   // (2,3)

    // 2. fused cross-lane CNOTs (4,5),(6,7),(8,9),(5,6),(7,8): one bperm/scalar
    #pragma unroll
    for (int r = 0; r < 32; r += 2) {
      v[r]     = bperm(addrE, v[r]);
      v[r + 1] = bperm(addrO, v[r + 1]);
    }

    // 3. reg-reg swaps for CNOT (1,2),(3,4)  [free SSA renames]
    #pragma unroll
    for (int r = 0; r < 32; ++r) if ((r & 12) == 8) { float t = v[r]; v[r] = v[r + 4]; v[r + 4] = t; }  // (1,2)
    #pragma unroll
    for (int r = 0; r < 32; ++r) if ((r & 3) == 2) { float t = v[r]; v[r] = v[r + 1]; v[r + 1] = t; }   // (3,4)

    // 4. RY gates (tan form)
    ry_reg_t<16>(v, cl[0]);   // q0
    ry_reg_t< 8>(v, cl[2]);   // q1
    ry_reg_t< 4>(v, cl[4]);   // q2
    ry_reg_t< 2>(v, cl[6]);   // q3
    ry_reg_t< 1>(v, cl[8]);   // q4
    // q5 (lane b4, ds_swizzle xor16): v += tsn * partner
    { float t = cl[10]; float tsn = (lane & 16) ? t : -t;
      #pragma unroll
      for (int r = 0; r < 32; ++r) v[r] = fmaf(tsn, xl16(v[r]), v[r]); }
    // q6 (lane b3, DPP row_ror:8)
    { float t = cl[12]; float tsn = (lane & 8) ? t : -t;
      #pragma unroll
      for (int r = 0; r < 32; ++r) v[r] = fmaf(tsn, xl8(v[r]), v[r]); }
    // q7 (lane b2, double-DPP xor4 on VALU)
    { float t = cl[14]; float tsn = (lane & 4) ? t : -t;
      #pragma unroll
      for (int r = 0; r < 32; ++r) v[r] = fmaf(tsn, xl4d(v[r]), v[r]); }
    // q8 (lane b1, DPP xor2)
    { float t = cl[16]; float tsn = (lane & 2) ? t : -t;
      #pragma unroll
      for (int r = 0; r < 32; ++r) v[r] = fmaf(tsn, xl2(v[r]), v[r]); }
    // q9 (lane b0, DPP xor1)
    { float t = cl[18]; float tsn = (lane & 1) ? t : -t;
      #pragma unroll
      for (int r = 0; r < 32; ++r) v[r] = fmaf(tsn, xl1(v[r]), v[r]); }

    // 5. per-layer rescale: restore the 10 cos factors of this layer
    { float ls = csh[160 + l];
      #pragma unroll
      for (int r = 0; r < 32; ++r) v[r] *= ls; }
  }

  // ---- expectation values (scaled by nn; fixed by inv at the store) ------
  float z[10];
  #pragma unroll
  for (int r = 0; r < 32; ++r) v[r] *= v[r];   // probabilities * nn
  z[4] = red32(tree_level<16>(v));
  z[3] = red32(tree_level< 8>(v));
  z[2] = red32(tree_level< 4>(v));
  z[1] = red32(tree_level< 2>(v));
  z[0] = red32(tree_level< 1>(v));
  float W = v[0];  // per-lane total probability (scaled)
  // lane-bit qubits: signed reductions over the 32-lane group
  { float u = W + xl1(W); u += xl2(u); u += xl4(u); u += xl8(u);  float t = u - xl16(u); z[5] = (lane & 16) ? -t : t; }
  { float u = W + xl1(W); u += xl2(u); u += xl4(u); u += xl16(u); float t = u - xl8(u);  z[6] = (lane & 8)  ? -t : t; }
  { float u = W + xl1(W); u += xl2(u); u += xl8(u); u += xl16(u); float t = u - xl4(u);  z[7] = (lane & 4)  ? -t : t; }
  { float u = W + xl1(W); u += xl4(u); u += xl8(u); u += xl16(u); float t = u - xl2(u);  z[8] = (lane & 2)  ? -t : t; }
  { float u = W + xl2(W); u += xl4(u); u += xl8(u); u += xl16(u); float t = u - xl1(u);  z[9] = (lane & 1)  ? -t : t; }

  // ---- store: lane l5 (<10) writes column l5, normalized -----------------
  float o = z[0];
  #pragma unroll
  for (int j = 1; j < 10; ++j) o = (l5 == j) ? z[j] : o;
  if (l5 < 10) out[elem * 10 + l5] = o * inv;
}

extern "C" void kernel_launch(void* const* d_in, const int* in_sizes, int n_in,
                              void* d_out, int out_size, void* d_ws, size_t ws_size,
                              hipStream_t stream) {
  const float* x      = (const float*)d_in[0];   // [16384, 784]
  const float* params = (const float*)d_in[1];   // [8, 10]
  float* out          = (float*)d_out;           // [16384, 10]
  (void)d_ws; (void)ws_size; (void)in_sizes; (void)n_in; (void)out_size;
  // 16384 elements / 8 per block (2 per wave x 4 waves)
  circuit_kernel<<<2048, 256, 0, stream>>>(x, params, out);
}

// Round 17
// 59.636 us; speedup vs baseline: 1.3538x; 1.0331x over previous
//
#include <hip/hip_runtime.h>
#include <math.h>

// 10-qubit real-amplitude circuit simulator, batch 16384, depth 8.
// Layout (R10-proven): 32 lanes per batch element (index bits [4:0]=lane&31),
//         16 x v2f (=32 scalars) per lane; scalar s = u*2 + comp.
// Qubit map: q0..q3 -> u bits 3..0 ; q4 -> float2 component ;
//            q5..q9 -> lane bits 4..0.
// 2 elements per wave (lane bit 5), 8 per 256-thread block.
//
// vs round 16 (scalar tan-form, VALU-bound 86-94% @ 61.6us): tan-form gates
// on the packed v2f skeleton (R10). Reg gates: 2 pk-FMA/pair. q4: swap +
// 1 pk-FMA with (-t,t). Lane gates: partner fetch + 1 pk-FMA. Per-layer
// rescale by the layer's 10-cos product (16 pk-mul) keeps fp32 bounded
// (R15's global-scale overflow fix, R16-verified).

typedef float v2f __attribute__((ext_vector_type(2)));

// ---- cross-lane helpers -------------------------------------------------
template<int CTRL>
__device__ __forceinline__ float dpp_mov(float x) {
  int i = __builtin_bit_cast(int, x);
  i = __builtin_amdgcn_update_dpp(i, i, CTRL, 0xf, 0xf, true);
  return __builtin_bit_cast(float, i);
}
__device__ __forceinline__ float xl1(float x) { return dpp_mov<0xB1>(x); }   // lane^1
__device__ __forceinline__ float xl2(float x) { return dpp_mov<0x4E>(x); }   // lane^2
__device__ __forceinline__ float xl8(float x) { return dpp_mov<0x128>(x); }  // row_ror:8 == lane^8
__device__ __forceinline__ float xl4d(float x) {                             // lane^4 via 2 DPP (VALU)
  return dpp_mov<0x141>(dpp_mov<0x1B>(x));   // row_half_mirror o quad_perm[3,2,1,0]
}
template<int PAT>
__device__ __forceinline__ float swz(float x) {  // ds_swizzle BitMode
  int i = __builtin_amdgcn_ds_swizzle(__builtin_bit_cast(int, x), PAT);
  return __builtin_bit_cast(float, i);
}
__device__ __forceinline__ float xl4(float x)  { return swz<0x101F>(x); }    // lane^4 (epilogue only)
__device__ __forceinline__ float xl16(float x) { return swz<0x401F>(x); }    // lane^16
__device__ __forceinline__ float bperm(int addr, float x) {
  int i = __builtin_amdgcn_ds_bpermute(addr, __builtin_bit_cast(int, x));
  return __builtin_bit_cast(float, i);
}
__device__ __forceinline__ float red32(float x) {
  x += xl1(x); x += xl2(x); x += xl4(x); x += xl8(x); x += xl16(x); return x;
}

// ---- one level of the sum/diff tree -------------------------------------
template<int L2>
__device__ __forceinline__ float tree_level(float* t) {
  float a = 0.f, b = 0.f;
  #pragma unroll
  for (int j = 0; j < L2; ++j) {
    float e = t[2 * j], o = t[2 * j + 1];
    if (j & 1) b += e - o; else a += e - o;
    t[j] = e + o;
  }
  return a + b;
}

__global__ __launch_bounds__(256, 6) void circuit_kernel(
    const float* __restrict__ x, const float* __restrict__ params,
    float* __restrict__ out) {
  // csh[2g]=tan(th/2), csh[2g+1]=cos(th/2), g=l*10+q; csh[160+l]=layer cos-product
  __shared__ float csh[168];

  const int tid  = threadIdx.x;
  const int wv   = tid >> 6;
  const int lane = tid & 63;
  const int h    = lane >> 5;   // element within wave (0..1)
  const int l5   = lane & 31;   // lane within group = index bits [4:0]
  const long elem = (long)blockIdx.x * 8 + wv * 2 + h;

  if (tid < 80) {
    float th = 1.57079632679489662f * tanhf(params[tid]);  // (pi*tanh)/2
    float c = cosf(th), s = sinf(th);
    csh[2 * tid]     = s / c;   // tan(th/2)
    csh[2 * tid + 1] = c;
  }

  // bpermute pull map (inverse of push (4,5),(6,7),(8,9),(5,6),(7,8)):
  //   m = l5; b1^=b2; b3^=b4; b0^=b1; b2^=b3; [odd scalar: b4^=1]
  int m = l5 ^ ((l5 & 4) >> 1);   // undo (7,8)
  m ^= (m & 16) >> 1;             // undo (5,6)
  m ^= (m & 2) >> 1;              // undo (8,9)
  m ^= (m & 8) >> 1;              // undo (6,7)
  const int addrE = ((lane & 32) | m) << 2;  // even scalar (.x) source
  const int addrO = addrE ^ 64;              // odd scalar (.y): lane b4 flips

  // ---- load: scalar s at x[s*32 + l5]; s = 2u (+1 for .y) ----------------
  v2f w[16];
  const float* xb = x + elem * 784 + l5;
  #pragma unroll
  for (int u = 0; u < 12; ++u) {
    w[u].x = xb[u * 64];
    w[u].y = xb[u * 64 + 32];
  }
  w[12].x = (l5 < 16) ? xb[768] : 0.f;
  w[12].y = 0.f;
  #pragma unroll
  for (int u = 13; u < 16; ++u) w[u] = (v2f){0.f, 0.f};

  // ---- norm^2 only (normalization deferred to the store) -----------------
  v2f acc = {0.f, 0.f};
  #pragma unroll
  for (int u = 0; u < 13; ++u) acc += w[u] * w[u];
  float nn  = red32(acc.x + acc.y);
  float inv = 1.0f / nn;

  __syncthreads();   // csh t/c entries ready
  if (tid < 8) {     // per-layer scale: product of this layer's 10 cos
    float P = 1.f;
    #pragma unroll
    for (int q = 0; q < 10; ++q) P *= csh[tid * 20 + 2 * q + 1];
    csh[160 + tid] = P;
  }
  __syncthreads();   // layer scales ready

  // ---- 8 layers, fully unrolled, packed tan-form -------------------------
  #pragma unroll
  for (int l = 0; l < 8; ++l) {
    const float* cl = &csh[l * 20];

    // 1. reg swaps for CNOT (0,1),(2,3)  [free SSA renames]
    #pragma unroll
    for (int u = 0; u < 16; ++u) if ((u & 12) == 8) { v2f t = w[u]; w[u] = w[u + 4]; w[u + 4] = t; } // (0,1)
    #pragma unroll
    for (int u = 0; u < 16; ++u) if ((u & 3) == 2) { v2f t = w[u]; w[u] = w[u + 1]; w[u + 1] = t; }  // (2,3)

    // 2. fused cross-lane CNOTs (4,5),(6,7),(8,9),(5,6),(7,8)
    #pragma unroll
    for (int u = 0; u < 16; ++u) {
      w[u].x = bperm(addrE, w[u].x);
      w[u].y = bperm(addrO, w[u].y);
    }

    // 3. reg swaps for CNOT (1,2); (3,4) = component swap for odd u
    #pragma unroll
    for (int u = 0; u < 16; ++u) if ((u & 6) == 4) { v2f t = w[u]; w[u] = w[u + 2]; w[u + 2] = t; }  // (1,2)
    #pragma unroll
    for (int u = 1; u < 16; u += 2) w[u] = __builtin_shufflevector(w[u], w[u], 1, 0);                // (3,4)

    // 4. RY q0..q3 (tan form, packed): (a,b) -> (a - t*b, b + t*a)
    { v2f tt = {cl[0], cl[0]};
      #pragma unroll
      for (int u = 0; u < 16; ++u) if ((u & 8) == 0) {
        v2f a = w[u], b = w[u + 8];
        w[u] = a - tt * b;  w[u + 8] = b + tt * a;
      } }
    { v2f tt = {cl[2], cl[2]};
      #pragma unroll
      for (int u = 0; u < 16; ++u) if ((u & 4) == 0) {
        v2f a = w[u], b = w[u + 4];
        w[u] = a - tt * b;  w[u + 4] = b + tt * a;
      } }
    { v2f tt = {cl[4], cl[4]};
      #pragma unroll
      for (int u = 0; u < 16; ++u) if ((u & 2) == 0) {
        v2f a = w[u], b = w[u + 2];
        w[u] = a - tt * b;  w[u + 2] = b + tt * a;
      } }
    { v2f tt = {cl[6], cl[6]};
      #pragma unroll
      for (int u = 0; u < 16; ++u) if ((u & 1) == 0) {
        v2f a = w[u], b = w[u + 1];
        w[u] = a - tt * b;  w[u + 1] = b + tt * a;
      } }

    // RY q4 (component, tan form): w' = w + (-t,t) (.) swap(w)
    { v2f tv = {-cl[8], cl[8]};
      #pragma unroll
      for (int u = 0; u < 16; ++u) {
        v2f sw = __builtin_shufflevector(w[u], w[u], 1, 0);
        w[u] = w[u] + tv * sw;
      } }

    // RY q5 (lane b4, ds_swizzle xor16): w += tsn * partner
    { float t = cl[10]; float tsn = (lane & 16) ? t : -t;
      v2f tv = {tsn, tsn};
      #pragma unroll
      for (int u = 0; u < 16; ++u) {
        v2f p = { xl16(w[u].x), xl16(w[u].y) };
        w[u] = w[u] + tv * p;
      } }
    // RY q6 (lane b3, DPP row_ror:8)
    { float t = cl[12]; float tsn = (lane & 8) ? t : -t;
      v2f tv = {tsn, tsn};
      #pragma unroll
      for (int u = 0; u < 16; ++u) {
        v2f p = { xl8(w[u].x), xl8(w[u].y) };
        w[u] = w[u] + tv * p;
      } }
    // RY q7 (lane b2, double-DPP xor4 on VALU)
    { float t = cl[14]; float tsn = (lane & 4) ? t : -t;
      v2f tv = {tsn, tsn};
      #pragma unroll
      for (int u = 0; u < 16; ++u) {
        v2f p = { xl4d(w[u].x), xl4d(w[u].y) };
        w[u] = w[u] + tv * p;
      } }
    // RY q8 (lane b1, DPP xor2)
    { float t = cl[16]; float tsn = (lane & 2) ? t : -t;
      v2f tv = {tsn, tsn};
      #pragma unroll
      for (int u = 0; u < 16; ++u) {
        v2f p = { xl2(w[u].x), xl2(w[u].y) };
        w[u] = w[u] + tv * p;
      } }
    // RY q9 (lane b0, DPP xor1)
    { float t = cl[18]; float tsn = (lane & 1) ? t : -t;
      v2f tv = {tsn, tsn};
      #pragma unroll
      for (int u = 0; u < 16; ++u) {
        v2f p = { xl1(w[u].x), xl1(w[u].y) };
        w[u] = w[u] + tv * p;
      } }

    // 5. per-layer rescale (restore this layer's 10 cos factors)
    { float ls = csh[160 + l];
      v2f lv = {ls, ls};
      #pragma unroll
      for (int u = 0; u < 16; ++u) w[u] *= lv;
    }
  }

  // ---- expectation values (scaled by nn; fixed by inv at the store) ------
  #pragma unroll
  for (int u = 0; u < 16; ++u) w[u] *= w[u];   // probabilities * nn

  float t16[16];
  float a0 = 0.f, a1 = 0.f;
  #pragma unroll
  for (int u = 0; u < 16; ++u) {
    float d = w[u].x - w[u].y;
    if (u & 1) a1 += d; else a0 += d;
    t16[u] = w[u].x + w[u].y;
  }
  float z[10];
  z[4] = red32(a0 + a1);
  z[3] = red32(tree_level<8>(t16));
  z[2] = red32(tree_level<4>(t16));
  z[1] = red32(tree_level<2>(t16));
  z[0] = red32(tree_level<1>(t16));
  float W = t16[0];  // per-lane total probability (scaled)
  // lane-bit qubits: signed reductions over the 32-lane group
  { float u = W + xl1(W); u += xl2(u); u += xl4(u); u += xl8(u);  float t = u - xl16(u); z[5] = (lane & 16) ? -t : t; }
  { float u = W + xl1(W); u += xl2(u); u += xl4(u); u += xl16(u); float t = u - xl8(u);  z[6] = (lane & 8)  ? -t : t; }
  { float u = W + xl1(W); u += xl2(u); u += xl8(u); u += xl16(u); float t = u - xl4(u);  z[7] = (lane & 4)  ? -t : t; }
  { float u = W + xl1(W); u += xl4(u); u += xl8(u); u += xl16(u); float t = u - xl2(u);  z[8] = (lane & 2)  ? -t : t; }
  { float u = W + xl2(W); u += xl4(u); u += xl8(u); u += xl16(u); float t = u - xl1(u);  z[9] = (lane & 1)  ? -t : t; }

  // ---- store: lane l5 (<10) writes column l5, normalized -----------------
  float o = z[0];
  #pragma unroll
  for (int j = 1; j < 10; ++j) o = (l5 == j) ? z[j] : o;
  if (l5 < 10) out[elem * 10 + l5] = o * inv;
}

extern "C" void kernel_launch(void* const* d_in, const int* in_sizes, int n_in,
                              void* d_out, int out_size, void* d_ws, size_t ws_size,
                              hipStream_t stream) {
  const float* x      = (const float*)d_in[0];   // [16384, 784]
  const float* params = (const float*)d_in[1];   // [8, 10]
  float* out          = (float*)d_out;           // [16384, 10]
  (void)d_ws; (void)ws_size; (void)in_sizes; (void)n_in; (void)out_size;
  // 16384 elements / 8 per block (2 per wave x 4 waves)
  circuit_kernel<<<2048, 256, 0, stream>>>(x, params, out);
}

// Round 20
// 59.517 us; speedup vs baseline: 1.3565x; 1.0020x over previous
//
#include <hip/hip_runtime.h>
#include <math.h>

// 10-qubit real-amplitude circuit simulator, batch 16384, depth 8.
// Layout (R10/R17-proven): 32 lanes per batch element (index bits [4:0]),
//         16 x v2f (=32 scalars) per lane; scalar s = u*2 + comp.
// Qubit map: q0..q3 -> u bits 3..0 ; q4 -> float2 component ;
//            q5..q9 -> lane bits 4..0.
// 2 elements per wave (lane bit 5), 8 per 256-thread block.
//
// This is the round-17 kernel (verified 59.6 us): packed v2f tan-form gates
// with per-layer cos-product rescale. Rounds 18/19 (permlane16_swap for the
// xor16 partner) both failed correctness -- that instruction's semantics
// don't match the model; retired. DS per layer: 32 bperm + 32 ds_swizzle.

typedef float v2f __attribute__((ext_vector_type(2)));

// ---- cross-lane helpers -------------------------------------------------
template<int CTRL>
__device__ __forceinline__ float dpp_mov(float x) {
  int i = __builtin_bit_cast(int, x);
  i = __builtin_amdgcn_update_dpp(i, i, CTRL, 0xf, 0xf, true);
  return __builtin_bit_cast(float, i);
}
__device__ __forceinline__ float xl1(float x) { return dpp_mov<0xB1>(x); }   // lane^1
__device__ __forceinline__ float xl2(float x) { return dpp_mov<0x4E>(x); }   // lane^2
__device__ __forceinline__ float xl8(float x) { return dpp_mov<0x128>(x); }  // row_ror:8 == lane^8
__device__ __forceinline__ float xl4d(float x) {                             // lane^4 via 2 DPP (VALU)
  return dpp_mov<0x141>(dpp_mov<0x1B>(x));   // row_half_mirror o quad_perm[3,2,1,0]
}
template<int PAT>
__device__ __forceinline__ float swz(float x) {  // ds_swizzle BitMode
  int i = __builtin_amdgcn_ds_swizzle(__builtin_bit_cast(int, x), PAT);
  return __builtin_bit_cast(float, i);
}
__device__ __forceinline__ float xl4(float x)  { return swz<0x101F>(x); }    // lane^4 (epilogue only)
__device__ __forceinline__ float xl16(float x) { return swz<0x401F>(x); }    // lane^16
__device__ __forceinline__ float bperm(int addr, float x) {
  int i = __builtin_amdgcn_ds_bpermute(addr, __builtin_bit_cast(int, x));
  return __builtin_bit_cast(float, i);
}
__device__ __forceinline__ float red32(float x) {
  x += xl1(x); x += xl2(x); x += xl4(x); x += xl8(x); x += xl16(x); return x;
}

// ---- one level of the sum/diff tree -------------------------------------
template<int L2>
__device__ __forceinline__ float tree_level(float* t) {
  float a = 0.f, b = 0.f;
  #pragma unroll
  for (int j = 0; j < L2; ++j) {
    float e = t[2 * j], o = t[2 * j + 1];
    if (j & 1) b += e - o; else a += e - o;
    t[j] = e + o;
  }
  return a + b;
}

__global__ __launch_bounds__(256, 6) void circuit_kernel(
    const float* __restrict__ x, const float* __restrict__ params,
    float* __restrict__ out) {
  // csh[2g]=tan(th/2), csh[2g+1]=cos(th/2), g=l*10+q; csh[160+l]=layer cos-product
  __shared__ float csh[168];

  const int tid  = threadIdx.x;
  const int wv   = tid >> 6;
  const int lane = tid & 63;
  const int h    = lane >> 5;   // element within wave (0..1)
  const int l5   = lane & 31;   // lane within group = index bits [4:0]
  const long elem = (long)blockIdx.x * 8 + wv * 2 + h;

  if (tid < 80) {
    float th = 1.57079632679489662f * tanhf(params[tid]);  // (pi*tanh)/2
    float c = cosf(th), s = sinf(th);
    csh[2 * tid]     = s / c;   // tan(th/2)
    csh[2 * tid + 1] = c;
  }

  // bpermute pull map (inverse of push (4,5),(6,7),(8,9),(5,6),(7,8)):
  //   m = l5; b1^=b2; b3^=b4; b0^=b1; b2^=b3; [odd scalar: b4^=1]
  int m = l5 ^ ((l5 & 4) >> 1);   // undo (7,8)
  m ^= (m & 16) >> 1;             // undo (5,6)
  m ^= (m & 2) >> 1;              // undo (8,9)
  m ^= (m & 8) >> 1;              // undo (6,7)
  const int addrE = ((lane & 32) | m) << 2;  // even scalar (.x) source
  const int addrO = addrE ^ 64;              // odd scalar (.y): lane b4 flips

  // ---- load: scalar s at x[s*32 + l5]; s = 2u (+1 for .y) ----------------
  v2f w[16];
  const float* xb = x + elem * 784 + l5;
  #pragma unroll
  for (int u = 0; u < 12; ++u) {
    w[u].x = xb[u * 64];
    w[u].y = xb[u * 64 + 32];
  }
  w[12].x = (l5 < 16) ? xb[768] : 0.f;
  w[12].y = 0.f;
  #pragma unroll
  for (int u = 13; u < 16; ++u) w[u] = (v2f){0.f, 0.f};

  // ---- norm^2 only (normalization deferred to the store) -----------------
  v2f acc = {0.f, 0.f};
  #pragma unroll
  for (int u = 0; u < 13; ++u) acc += w[u] * w[u];
  float nn  = red32(acc.x + acc.y);
  float inv = 1.0f / nn;

  __syncthreads();   // csh t/c entries ready
  if (tid < 8) {     // per-layer scale: product of this layer's 10 cos
    float P = 1.f;
    #pragma unroll
    for (int q = 0; q < 10; ++q) P *= csh[tid * 20 + 2 * q + 1];
    csh[160 + tid] = P;
  }
  __syncthreads();   // layer scales ready

  // ---- 8 layers, fully unrolled, packed tan-form -------------------------
  #pragma unroll
  for (int l = 0; l < 8; ++l) {
    const float* cl = &csh[l * 20];

    // 1. reg swaps for CNOT (0,1),(2,3)  [free SSA renames]
    #pragma unroll
    for (int u = 0; u < 16; ++u) if ((u & 12) == 8) { v2f t = w[u]; w[u] = w[u + 4]; w[u + 4] = t; } // (0,1)
    #pragma unroll
    for (int u = 0; u < 16; ++u) if ((u & 3) == 2) { v2f t = w[u]; w[u] = w[u + 1]; w[u + 1] = t; }  // (2,3)

    // 2. fused cross-lane CNOTs (4,5),(6,7),(8,9),(5,6),(7,8)
    #pragma unroll
    for (int u = 0; u < 16; ++u) {
      w[u].x = bperm(addrE, w[u].x);
      w[u].y = bperm(addrO, w[u].y);
    }

    // 3. reg swaps for CNOT (1,2); (3,4) = component swap for odd u
    #pragma unroll
    for (int u = 0; u < 16; ++u) if ((u & 6) == 4) { v2f t = w[u]; w[u] = w[u + 2]; w[u + 2] = t; }  // (1,2)
    #pragma unroll
    for (int u = 1; u < 16; u += 2) w[u] = __builtin_shufflevector(w[u], w[u], 1, 0);                // (3,4)

    // 4. RY q0..q3 (tan form, packed): (a,b) -> (a - t*b, b + t*a)
    { v2f tt = {cl[0], cl[0]};
      #pragma unroll
      for (int u = 0; u < 16; ++u) if ((u & 8) == 0) {
        v2f a = w[u], b = w[u + 8];
        w[u] = a - tt * b;  w[u + 8] = b + tt * a;
      } }
    { v2f tt = {cl[2], cl[2]};
      #pragma unroll
      for (int u = 0; u < 16; ++u) if ((u & 4) == 0) {
        v2f a = w[u], b = w[u + 4];
        w[u] = a - tt * b;  w[u + 4] = b + tt * a;
      } }
    { v2f tt = {cl[4], cl[4]};
      #pragma unroll
      for (int u = 0; u < 16; ++u) if ((u & 2) == 0) {
        v2f a = w[u], b = w[u + 2];
        w[u] = a - tt * b;  w[u + 2] = b + tt * a;
      } }
    { v2f tt = {cl[6], cl[6]};
      #pragma unroll
      for (int u = 0; u < 16; ++u) if ((u & 1) == 0) {
        v2f a = w[u], b = w[u + 1];
        w[u] = a - tt * b;  w[u + 1] = b + tt * a;
      } }

    // RY q4 (component, tan form): w' = w + (-t,t) (.) swap(w)
    { v2f tv = {-cl[8], cl[8]};
      #pragma unroll
      for (int u = 0; u < 16; ++u) {
        v2f sw = __builtin_shufflevector(w[u], w[u], 1, 0);
        w[u] = w[u] + tv * sw;
      } }

    // RY q5 (lane b4, ds_swizzle xor16): w += tsn * partner
    { float t = cl[10]; float tsn = (lane & 16) ? t : -t;
      v2f tv = {tsn, tsn};
      #pragma unroll
      for (int u = 0; u < 16; ++u) {
        v2f p = { xl16(w[u].x), xl16(w[u].y) };
        w[u] = w[u] + tv * p;
      } }
    // RY q6 (lane b3, DPP row_ror:8)
    { float t = cl[12]; float tsn = (lane & 8) ? t : -t;
      v2f tv = {tsn, tsn};
      #pragma unroll
      for (int u = 0; u < 16; ++u) {
        v2f p = { xl8(w[u].x), xl8(w[u].y) };
        w[u] = w[u] + tv * p;
      } }
    // RY q7 (lane b2, double-DPP xor4 on VALU)
    { float t = cl[14]; float tsn = (lane & 4) ? t : -t;
      v2f tv = {tsn, tsn};
      #pragma unroll
      for (int u = 0; u < 16; ++u) {
        v2f p = { xl4d(w[u].x), xl4d(w[u].y) };
        w[u] = w[u] + tv * p;
      } }
    // RY q8 (lane b1, DPP xor2)
    { float t = cl[16]; float tsn = (lane & 2) ? t : -t;
      v2f tv = {tsn, tsn};
      #pragma unroll
      for (int u = 0; u < 16; ++u) {
        v2f p = { xl2(w[u].x), xl2(w[u].y) };
        w[u] = w[u] + tv * p;
      } }
    // RY q9 (lane b0, DPP xor1)
    { float t = cl[18]; float tsn = (lane & 1) ? t : -t;
      v2f tv = {tsn, tsn};
      #pragma unroll
      for (int u = 0; u < 16; ++u) {
        v2f p = { xl1(w[u].x), xl1(w[u].y) };
        w[u] = w[u] + tv * p;
      } }

    // 5. per-layer rescale (restore this layer's 10 cos factors)
    { float ls = csh[160 + l];
      v2f lv = {ls, ls};
      #pragma unroll
      for (int u = 0; u < 16; ++u) w[u] *= lv;
    }
  }

  // ---- expectation values (scaled by nn; fixed by inv at the store) ------
  #pragma unroll
  for (int u = 0; u < 16; ++u) w[u] *= w[u];   // probabilities * nn

  float t16[16];
  float a0 = 0.f, a1 = 0.f;
  #pragma unroll
  for (int u = 0; u < 16; ++u) {
    float d = w[u].x - w[u].y;
    if (u & 1) a1 += d; else a0 += d;
    t16[u] = w[u].x + w[u].y;
  }
  float z[10];
  z[4] = red32(a0 + a1);
  z[3] = red32(tree_level<8>(t16));
  z[2] = red32(tree_level<4>(t16));
  z[1] = red32(tree_level<2>(t16));
  z[0] = red32(tree_level<1>(t16));
  float W = t16[0];  // per-lane total probability (scaled)
  // lane-bit qubits: signed reductions over the 32-lane group
  { float u = W + xl1(W); u += xl2(u); u += xl4(u); u += xl8(u);  float t = u - xl16(u); z[5] = (lane & 16) ? -t : t; }
  { float u = W + xl1(W); u += xl2(u); u += xl4(u); u += xl16(u); float t = u - xl8(u);  z[6] = (lane & 8)  ? -t : t; }
  { float u = W + xl1(W); u += xl2(u); u += xl8(u); u += xl16(u); float t = u - xl4(u);  z[7] = (lane & 4)  ? -t : t; }
  { float u = W + xl1(W); u += xl4(u); u += xl8(u); u += xl16(u); float t = u - xl2(u);  z[8] = (lane & 2)  ? -t : t; }
  { float u = W + xl2(W); u += xl4(u); u += xl8(u); u += xl16(u); float t = u - xl1(u);  z[9] = (lane & 1)  ? -t : t; }

  // ---- store: lane l5 (<10) writes column l5, normalized -----------------
  float o = z[0];
  #pragma unroll
  for (int j = 1; j < 10; ++j) o = (l5 == j) ? z[j] : o;
  if (l5 < 10) out[elem * 10 + l5] = o * inv;
}

extern "C" void kernel_launch(void* const* d_in, const int* in_sizes, int n_in,
                              void* d_out, int out_size, void* d_ws, size_t ws_size,
                              hipStream_t stream) {
  const float* x      = (const float*)d_in[0];   // [16384, 784]
  const float* params = (const float*)d_in[1];   // [8, 10]
  float* out          = (float*)d_out;           // [16384, 10]
  (void)d_ws; (void)ws_size; (void)in_sizes; (void)n_in; (void)out_size;
  // 16384 elements / 8 per block (2 per wave x 4 waves)
  circuit_kernel<<<2048, 256, 0, stream>>>(x, params, out);
}